// Round 10
// baseline (253.376 us; speedup 1.0000x reference)
//
#include <hip/hip_runtime.h>

#define N_NODES 20000
#define N_REL 200
#define N_EDGES 200000
#define DIM 128
#define T_STEPS 8
#define N_TILES (N_NODES / 16)              // 1250
#define KEYS (N_NODES * T_STEPS)            // 160000 (dst,t) segments
#define SCAN_N (KEYS + 1)                   // 160001
#define SCAN_BLKS ((SCAN_N + 1023) / 1024)  // 157

typedef short short8 __attribute__((ext_vector_type(8)));
typedef float f32x4 __attribute__((ext_vector_type(4)));

static __device__ __forceinline__ unsigned short f2bf(float f) {
  union { float f; unsigned u; } v; v.f = f;
  unsigned r = v.u + 0x7fffu + ((v.u >> 16) & 1u);   // RNE
  return (unsigned short)(r >> 16);
}
// packed f32x2 -> bf16x2 (RNE), 1 instruction
static __device__ __forceinline__ unsigned cvt_pk_bf16(float lo, float hi) {
  unsigned r;
  asm("v_cvt_pk_bf16_f32 %0, %1, %2" : "=v"(r) : "v"(lo), "v"(hi));
  return r;
}
static __device__ __forceinline__ float fast_tanh(float x) {
  float e = __expf(2.f * x);           // inf-safe: x>>0 -> 1, x<<0 -> -1
  return 1.f - 2.f / (e + 1.f);
}
static __device__ __forceinline__ float fast_sig(float x) {
  return 1.f / (1.f + __expf(-x));
}

// ---------------------------------------------------------------------------
// Repack the five 128x128 fp32 weight matrices (row-major W[k][n]) into bf16
// MFMA B-fragment order: pack[m][((nt*4+ks)*64+lane)*8+j] = bf16(W[k][n]),
// n = nt*16 + (lane&15), k = ks*32 + (lane>>4)*8 + j.
// Slots: 0=Wenc 1=Wz 2=Uz 3=Wh 4=Uh.
// ---------------------------------------------------------------------------
__global__ void repack5(const float* __restrict__ w0,
                        const float* __restrict__ w1,
                        const float* __restrict__ w2,
                        const float* __restrict__ w3,
                        const float* __restrict__ w4,
                        unsigned short* __restrict__ pack) {
  int i = blockIdx.x * blockDim.x + threadIdx.x;
  if (i >= 5 * 16384) return;
  int m = i >> 14, r = i & 16383;
  int j = r & 7, lane = (r >> 3) & 63, ks = (r >> 9) & 3, nt = (r >> 11) & 7;
  int n = nt * 16 + (lane & 15);
  int k = ks * 32 + (lane >> 4) * 8 + j;
  const float* w = (m == 0) ? w0 : (m == 1) ? w1 : (m == 2) ? w2
                 : (m == 3) ? w3 : w4;
  pack[i] = f2bf(w[k * DIM + n]);
}

// ----------------- CSR build: bucket by key = dst*8 + t --------------------
__global__ void hist_k(const int* __restrict__ dst, const int* __restrict__ etime,
                       int* __restrict__ counts) {
  int i = blockIdx.x * blockDim.x + threadIdx.x;
  if (i >= N_EDGES) return;
  atomicAdd(&counts[dst[i] * T_STEPS + etime[i]], 1);
}

__global__ void scan1_k(const int* __restrict__ counts,
                        int* __restrict__ base, int* __restrict__ bsum) {
  __shared__ int ls[256];
  int tid = threadIdx.x;
  int i0 = blockIdx.x * 1024 + tid * 4;
  int v[4], ts = 0;
#pragma unroll
  for (int r = 0; r < 4; r++) {
    v[r] = (i0 + r < SCAN_N) ? counts[i0 + r] : 0;
    ts += v[r];
  }
  ls[tid] = ts; __syncthreads();
#pragma unroll
  for (int off = 1; off < 256; off <<= 1) {
    int x = (tid >= off) ? ls[tid - off] : 0;
    __syncthreads(); ls[tid] += x; __syncthreads();
  }
  int run = ls[tid] - ts;
  if (tid == 255) bsum[blockIdx.x] = ls[255];
#pragma unroll
  for (int r = 0; r < 4; r++) {
    if (i0 + r < SCAN_N) base[i0 + r] = run;
    run += v[r];
  }
}

__global__ void scan2_k(int* __restrict__ bsum) {
  __shared__ int ls[256];
  int tid = threadIdx.x;
  int v = (tid < SCAN_BLKS) ? bsum[tid] : 0;
  ls[tid] = v; __syncthreads();
#pragma unroll
  for (int off = 1; off < 256; off <<= 1) {
    int x = (tid >= off) ? ls[tid - off] : 0;
    __syncthreads(); ls[tid] += x; __syncthreads();
  }
  if (tid < SCAN_BLKS) bsum[tid] = ls[tid] - v;
}

// ep2 = {src | rel<<15, weight bits}; t is implicit in the segment.
// scan3 folded in: absolute position = base[key] + bsum[key>>10] + cursor++.
__global__ void fill_k(const int* __restrict__ src, const int* __restrict__ dst,
                       const int* __restrict__ etype, const int* __restrict__ etime,
                       const float* __restrict__ ew,
                       const int* __restrict__ base, const int* __restrict__ bsum,
                       int* __restrict__ cursor, uint2* __restrict__ ep2) {
  int i = blockIdx.x * blockDim.x + threadIdx.x;
  if (i >= N_EDGES) return;
  int key = dst[i] * T_STEPS + etime[i];
  int pos = base[key] + bsum[key >> 10] + atomicAdd(&cursor[key], 1);
  uint2 e;
  e.x = (unsigned)src[i] | ((unsigned)etype[i] << 15);
  e.y = __float_as_uint(ew[i]);
  ep2[pos] = e;
}

// ---------------------------------------------------------------------------
// Fully-fused GATHER + encoder + GRU recurrence. One block per 16-node tile,
// 8 waves.
// KEY CHANGE vs R9: the recurrence's H-dependent matmuls are HOISTED out of
// the sequential t-loop. H[t] for all t is known after the encoder; only
// S@Uz / S@Uh is truly sequential. So:
//   Phase A  (gather, R6 serial form -- R9's b0[9]/b1[9] arrays spilled to
//            scratch, +10 MB WRITE_SIZE): 2 nodes/wave, 8 segments each,
//            packed-bf16 rows -> aggL.
//   Phase B  (encoder): 32 MFMAs vs wenc -> hpk[t] (packed bf16 H).
//   barrier; Phase B2a: write ALL H[t] into aggL (agg values are dead --
//            same shape, zero extra LDS); barrier.
//   Phase B2b: zh[t]=bz+H[t]@Wz, ch[t]=bh+H[t]@Wh for ALL 8 t: 64 MFMAs,
//            BARRIER-FREE, 4-deep chains -> overlaps freely across waves.
//            wz/wh die here; uz/uh loaded after (peak regs ~120).
//   Phase C  (sequential): t=0 needs NO barrier (S==0: S=sig(zh)*tanh(ch),
//            bit-exact). t=1..7: write S -> Sb[t&1], ONE barrier, read sA,
//            8 MFMAs (zs,cs chains of 4), gates with precomputed zh/ch.
//            Per-step convoy work ~halved vs R9; Hb deleted (LDS 52->43.5KB).
// Numerics: identical op sequence to R9 (H through bf16 LDS, zh+zs combine)
// -> absmax must remain 0.00831604.
// MFMA 16x16x32_bf16 layouts (HW-verified): A: m=lane&15,k=quad*8+j;
// B: n=lane&15,k=quad*8+j;  C/D: col=lane&15, row=quad*4+reg.
// Sb WAR safety: W(t) B(t) R(t) W(t+1)...: wave at W(t+2) passed B(t+1);
// every wave at B(t+1) completed R(t). aggL: all reads (B) fenced from H
// writes (B2a) by a barrier; all H writes fenced from B2b reads by a barrier.
// ---------------------------------------------------------------------------
__launch_bounds__(512, 3)
__global__ void fused_recur(const int* __restrict__ base,
                            const int* __restrict__ bsum,
                            const uint2* __restrict__ ep2,
                            const float* __restrict__ nemb,
                            const float* __restrict__ remb,
                            const unsigned short* __restrict__ pack,
                            const float* __restrict__ bz,
                            const float* __restrict__ bh,
                            float* __restrict__ out) {
  __shared__ unsigned short aggL[T_STEPS * 16 * 136];   // 34816 B (agg, then H)
  __shared__ unsigned short Sb[2][16 * 136];            //  8704 B
  int lane = threadIdx.x & 63;
  int nt = threadIdx.x >> 6;        // wave id: owns nodes {2nt,2nt+1} / col tile nt
  int q = lane >> 4, l15 = lane & 15;
  int tile = blockIdx.x;
  int row0 = tile * 16;
  int c = nt * 16 + l15;

  // ---- Phase A: gather this wave's 2 nodes, all 8 t-segments -> aggL ----
#pragma unroll
  for (int ln = 0; ln < 2; ln++) {
    int nl = nt * 2 + ln;                       // local row 0..15
    int kb = (row0 + nl) * T_STEPS;
    int prev = base[kb] + bsum[kb >> 10];
#pragma unroll
    for (int tt = 0; tt < T_STEPS; tt++) {
      int kn = kb + tt + 1;
      int e1 = base[kn] + bsum[kn >> 10];
      float ax = 0.f, ay = 0.f;
      for (int i = prev; i < e1; i++) {
        uint2 e = ep2[i];
        float w = __uint_as_float(e.y);
        int s = e.x & 0x7fff, rt = e.x >> 15;
        float2 sv = ((const float2*)(nemb + (size_t)s * DIM))[lane];
        float2 rv = ((const float2*)(remb + (size_t)rt * DIM))[lane];
        ax += sv.x * rv.x * w;
        ay += sv.y * rv.y * w;
      }
      prev = e1;
      ((unsigned*)&aggL[(tt * 16 + nl) * 136])[lane] = cvt_pk_bf16(ax, ay);
    }
  }
  __syncthreads();

  // ---- Phase B: encoder for ALL steps: H[t](:, nt-cols) as packed bf16 ----
  unsigned hpk[T_STEPS][2];
  {
    short8 wenc[4];
#pragma unroll
    for (int ks = 0; ks < 4; ks++)
      wenc[ks] = *(const short8*)(pack + ((nt * 4 + ks) * 64 + lane) * 8);
#pragma unroll
    for (int t = 0; t < T_STEPS; t++) {
      f32x4 acch = (f32x4){0.f, 0.f, 0.f, 0.f};
#pragma unroll
      for (int ks = 0; ks < 4; ks++) {
        short8 aA = *(const short8*)&aggL[(t * 16 + l15) * 136 + ks * 32 + q * 8];
        acch = __builtin_amdgcn_mfma_f32_16x16x32_bf16(aA, wenc[ks], acch, 0, 0, 0);
      }
      hpk[t][0] = cvt_pk_bf16(fast_tanh(acch[0]), fast_tanh(acch[1]));
      hpk[t][1] = cvt_pk_bf16(fast_tanh(acch[2]), fast_tanh(acch[3]));
    }
  }
  __syncthreads();                 // all aggL (agg) reads complete

  // ---- Phase B2a: all H[t] -> aggL (reuse) ----
#pragma unroll
  for (int t = 0; t < T_STEPS; t++) {
    int rbase = (t * 16 + q * 4) * 136 + c;
    aggL[rbase + 0 * 136] = (unsigned short)hpk[t][0];
    aggL[rbase + 1 * 136] = (unsigned short)(hpk[t][0] >> 16);
    aggL[rbase + 2 * 136] = (unsigned short)hpk[t][1];
    aggL[rbase + 3 * 136] = (unsigned short)(hpk[t][1] >> 16);
  }
  __syncthreads();                 // H visible to all waves

  // ---- Phase B2b: zh[t], ch[t] for ALL t (barrier-free, 64 MFMAs) ----
  f32x4 zh[T_STEPS], ch[T_STEPS];
  {
    short8 wzf[4], whf[4];
#pragma unroll
    for (int ks = 0; ks < 4; ks++) {
      int fo = ((nt * 4 + ks) * 64 + lane) * 8;
      wzf[ks] = *(const short8*)(pack + 16384 * 1 + fo);
      whf[ks] = *(const short8*)(pack + 16384 * 3 + fo);
    }
    float bzv = bz[c];
    float bhv = bh[c];
#pragma unroll
    for (int t = 0; t < T_STEPS; t++) {
      short8 hA[4];
#pragma unroll
      for (int ks = 0; ks < 4; ks++)
        hA[ks] = *(const short8*)&aggL[(t * 16 + l15) * 136 + ks * 32 + q * 8];
      f32x4 az = (f32x4){bzv, bzv, bzv, bzv};
      f32x4 ac = (f32x4){bhv, bhv, bhv, bhv};
#pragma unroll
      for (int ks = 0; ks < 4; ks++) {
        az = __builtin_amdgcn_mfma_f32_16x16x32_bf16(hA[ks], wzf[ks], az, 0, 0, 0);
        ac = __builtin_amdgcn_mfma_f32_16x16x32_bf16(hA[ks], whf[ks], ac, 0, 0, 0);
      }
      zh[t] = az;
      ch[t] = ac;
    }
  }

  // U-weight fragments (loaded after wz/wh die)
  short8 uz[4], uh[4];
#pragma unroll
  for (int ks = 0; ks < 4; ks++) {
    int fo = ((nt * 4 + ks) * 64 + lane) * 8;
    uz[ks] = *(const short8*)(pack + 16384 * 2 + fo);
    uh[ks] = *(const short8*)(pack + 16384 * 4 + fo);
  }

  // ---- Phase C: sequential recurrence (S-half only) ----
  f32x4 stC;
#pragma unroll
  for (int r = 0; r < 4; r++) {
    float z = fast_sig(zh[0][r]);
    float cc = fast_tanh(ch[0][r]);
    stC[r] = z * cc;                     // S0 = (1-z)*0 + z*c
  }

#pragma unroll
  for (int t = 1; t < T_STEPS; t++) {
    unsigned short* sB = Sb[t & 1];
    unsigned s01 = cvt_pk_bf16(stC[0], stC[1]);
    unsigned s23 = cvt_pk_bf16(stC[2], stC[3]);
    int rbase = (q * 4) * 136 + c;
    sB[rbase + 0 * 136] = (unsigned short)s01;
    sB[rbase + 1 * 136] = (unsigned short)(s01 >> 16);
    sB[rbase + 2 * 136] = (unsigned short)s23;
    sB[rbase + 3 * 136] = (unsigned short)(s23 >> 16);
    __syncthreads();

    short8 sA[4];
#pragma unroll
    for (int ks = 0; ks < 4; ks++)
      sA[ks] = *(const short8*)&sB[l15 * 136 + ks * 32 + q * 8];

    f32x4 zs = (f32x4){0.f, 0.f, 0.f, 0.f};
    f32x4 cs = (f32x4){0.f, 0.f, 0.f, 0.f};
#pragma unroll
    for (int ks = 0; ks < 4; ks++) {
      zs = __builtin_amdgcn_mfma_f32_16x16x32_bf16(sA[ks], uz[ks], zs, 0, 0, 0);
      cs = __builtin_amdgcn_mfma_f32_16x16x32_bf16(sA[ks], uh[ks], cs, 0, 0, 0);
    }
#pragma unroll
    for (int r = 0; r < 4; r++) {
      float z = fast_sig(zh[t][r] + zs[r]);
      float cc = fast_tanh(ch[t][r] + cs[r]);
      stC[r] = (1.f - z) * stC[r] + z * cc;
    }
  }

  // final state -> out (fp32, C-layout positions)
#pragma unroll
  for (int r = 0; r < 4; r++)
    out[(size_t)(row0 + q * 4 + r) * DIM + c] = stC[r];
}

extern "C" void kernel_launch(void* const* d_in, const int* in_sizes, int n_in,
                              void* d_out, int out_size, void* d_ws, size_t ws_size,
                              hipStream_t stream) {
  const int* eidx  = (const int*)d_in[0];
  const int* src   = eidx;
  const int* dst   = eidx + N_EDGES;
  const int* etype = (const int*)d_in[1];
  const int* etime = (const int*)d_in[2];
  const float* ew   = (const float*)d_in[3];
  const float* nemb = (const float*)d_in[4];
  const float* remb = (const float*)d_in[5];
  const float* Wenc = (const float*)d_in[6];
  const float* Wz   = (const float*)d_in[7];
  const float* Uz   = (const float*)d_in[8];
  const float* Wh   = (const float*)d_in[9];
  const float* Uh   = (const float*)d_in[10];
  const float* bz   = (const float*)d_in[11];
  const float* bh   = (const float*)d_in[12];
  // d_in[13] = num_times (constant 8 for this problem's fixed shapes)

  // ws layout
  int* counts = (int*)d_ws;                                        // SCAN_N
  int* cursor = counts + SCAN_N;                                   // KEYS
  int* bsum   = cursor + KEYS;                                     // 256
  int* base   = bsum + 256;                                        // SCAN_N
  uint2* ep2  = (uint2*)(base + ((SCAN_N + 1) & ~1));              // E, 8B-aligned
  unsigned short* pack = (unsigned short*)(ep2 + N_EDGES);         // 5*16384
  float* outp = (float*)d_out;

  hipMemsetAsync(counts, 0, (size_t)(SCAN_N + KEYS) * sizeof(int), stream);
  repack5<<<(5 * 16384 + 255) / 256, 256, 0, stream>>>(Wenc, Wz, Uz, Wh, Uh, pack);
  hist_k<<<(N_EDGES + 255) / 256, 256, 0, stream>>>(dst, etime, counts);
  scan1_k<<<SCAN_BLKS, 256, 0, stream>>>(counts, base, bsum);
  scan2_k<<<1, 256, 0, stream>>>(bsum);
  fill_k<<<(N_EDGES + 255) / 256, 256, 0, stream>>>(src, dst, etype, etime, ew,
                                                    base, bsum, cursor, ep2);
  fused_recur<<<N_TILES, 512, 0, stream>>>(base, bsum, ep2, nemb, remb,
                                           pack, bz, bh, outp);
}

// Round 11
// 215.526 us; speedup vs baseline: 1.1756x; 1.1756x over previous
//
#include <hip/hip_runtime.h>

#define N_NODES 20000
#define N_REL 200
#define N_EDGES 200000
#define DIM 128
#define T_STEPS 8
#define N_TILES (N_NODES / 16)              // 1250
#define KEYS (N_NODES * T_STEPS)            // 160000 (dst,t) segments
#define SCAN_N (KEYS + 1)                   // 160001
#define SCAN_BLKS ((SCAN_N + 1023) / 1024)  // 157

typedef short short8 __attribute__((ext_vector_type(8)));
typedef float f32x4 __attribute__((ext_vector_type(4)));

static __device__ __forceinline__ unsigned short f2bf(float f) {
  union { float f; unsigned u; } v; v.f = f;
  unsigned r = v.u + 0x7fffu + ((v.u >> 16) & 1u);   // RNE
  return (unsigned short)(r >> 16);
}
// packed f32x2 -> bf16x2 (RNE), 1 instruction
static __device__ __forceinline__ unsigned cvt_pk_bf16(float lo, float hi) {
  unsigned r;
  asm("v_cvt_pk_bf16_f32 %0, %1, %2" : "=v"(r) : "v"(lo), "v"(hi));
  return r;
}
static __device__ __forceinline__ float fast_tanh(float x) {
  float e = __expf(2.f * x);           // inf-safe: x>>0 -> 1, x<<0 -> -1
  return 1.f - 2.f / (e + 1.f);
}
static __device__ __forceinline__ float fast_sig(float x) {
  return 1.f / (1.f + __expf(-x));
}

// ---------------------------------------------------------------------------
// Repack the five 128x128 fp32 weight matrices (row-major W[k][n]) into bf16
// MFMA B-fragment order: pack[m][((nt*4+ks)*64+lane)*8+j] = bf16(W[k][n]),
// n = nt*16 + (lane&15), k = ks*32 + (lane>>4)*8 + j.
// Slots: 0=Wenc 1=Wz 2=Uz 3=Wh 4=Uh.
// ---------------------------------------------------------------------------
__global__ void repack5(const float* __restrict__ w0,
                        const float* __restrict__ w1,
                        const float* __restrict__ w2,
                        const float* __restrict__ w3,
                        const float* __restrict__ w4,
                        unsigned short* __restrict__ pack) {
  int i = blockIdx.x * blockDim.x + threadIdx.x;
  if (i >= 5 * 16384) return;
  int m = i >> 14, r = i & 16383;
  int j = r & 7, lane = (r >> 3) & 63, ks = (r >> 9) & 3, nt = (r >> 11) & 7;
  int n = nt * 16 + (lane & 15);
  int k = ks * 32 + (lane >> 4) * 8 + j;
  const float* w = (m == 0) ? w0 : (m == 1) ? w1 : (m == 2) ? w2
                 : (m == 3) ? w3 : w4;
  pack[i] = f2bf(w[k * DIM + n]);
}

// ----------------- CSR build: bucket by key = dst*8 + t --------------------
__global__ void hist_k(const int* __restrict__ dst, const int* __restrict__ etime,
                       int* __restrict__ counts) {
  int i = blockIdx.x * blockDim.x + threadIdx.x;
  if (i >= N_EDGES) return;
  atomicAdd(&counts[dst[i] * T_STEPS + etime[i]], 1);
}

__global__ void scan1_k(const int* __restrict__ counts,
                        int* __restrict__ base, int* __restrict__ bsum) {
  __shared__ int ls[256];
  int tid = threadIdx.x;
  int i0 = blockIdx.x * 1024 + tid * 4;
  int v[4], ts = 0;
#pragma unroll
  for (int r = 0; r < 4; r++) {
    v[r] = (i0 + r < SCAN_N) ? counts[i0 + r] : 0;
    ts += v[r];
  }
  ls[tid] = ts; __syncthreads();
#pragma unroll
  for (int off = 1; off < 256; off <<= 1) {
    int x = (tid >= off) ? ls[tid - off] : 0;
    __syncthreads(); ls[tid] += x; __syncthreads();
  }
  int run = ls[tid] - ts;
  if (tid == 255) bsum[blockIdx.x] = ls[255];
#pragma unroll
  for (int r = 0; r < 4; r++) {
    if (i0 + r < SCAN_N) base[i0 + r] = run;
    run += v[r];
  }
}

__global__ void scan2_k(int* __restrict__ bsum) {
  __shared__ int ls[256];
  int tid = threadIdx.x;
  int v = (tid < SCAN_BLKS) ? bsum[tid] : 0;
  ls[tid] = v; __syncthreads();
#pragma unroll
  for (int off = 1; off < 256; off <<= 1) {
    int x = (tid >= off) ? ls[tid - off] : 0;
    __syncthreads(); ls[tid] += x; __syncthreads();
  }
  if (tid < SCAN_BLKS) bsum[tid] = ls[tid] - v;
}

// ep2 = {src | rel<<15, weight bits}; t is implicit in the segment.
// scan3 folded in: absolute position = base[key] + bsum[key>>10] + cursor++.
__global__ void fill_k(const int* __restrict__ src, const int* __restrict__ dst,
                       const int* __restrict__ etype, const int* __restrict__ etime,
                       const float* __restrict__ ew,
                       const int* __restrict__ base, const int* __restrict__ bsum,
                       int* __restrict__ cursor, uint2* __restrict__ ep2) {
  int i = blockIdx.x * blockDim.x + threadIdx.x;
  if (i >= N_EDGES) return;
  int key = dst[i] * T_STEPS + etime[i];
  int pos = base[key] + bsum[key >> 10] + atomicAdd(&cursor[key], 1);
  uint2 e;
  e.x = (unsigned)src[i] | ((unsigned)etype[i] << 15);
  e.y = __float_as_uint(ew[i]);
  ep2[pos] = e;
}

// ---------------------------------------------------------------------------
// Fully-fused GATHER + encoder + GRU recurrence. One block per 16-node tile,
// 8 waves. Best-measured structure (R6 phase A + R9 phase C) with ONE new
// mechanism: LDS UNION. aggL (34816B) is dead after phase B; Hb/Sb (17408B)
// are used only in phase C -> Hb/Sb live INSIDE aggL's space. LDS 52224 ->
// 34816 B, occupancy 3 -> 4 blocks/CU (+33% resident waves to hide the
// latency-bound convoy -- all counters say no pipe >45% busy). Cost: one
// extra barrier between phase B's last aggL read and phase C's first write.
// Phase A (gather): wave wv owns nodes {2wv,2wv+1}, 8 CSR segments each,
//   serial walk (R9's interleave spilled registers: +10MB scratch traffic).
// Phase B (encoder): 32 MFMAs vs wenc -> hpk[t] packed bf16 (16 VGPRs).
// Phase C (recurrence): per step t: H[t] (and S for t>0) -> double-buffered
//   regions of the union, ONE barrier, re-read as A-frags, MFMAs in 4
//   independent 4-chains (zh,ch biased; zs,cs from 0, combined by fp32 add),
//   gates. t=0 skips the whole S path (S==0, bit-exact).
// MFMA 16x16x32_bf16 layouts (HW-verified): A: m=lane&15,k=quad*8+j;
// B: n=lane&15,k=quad*8+j;  C/D: col=lane&15, row=quad*4+reg.
// Union safety: post-B barrier fences all aggL(agg) reads from C's writes.
// Double-buffer WAR: W(t) B(t) R(t) W(t+1)...; wave at W(t+2) passed B(t+1);
// every wave at B(t+1) completed R(t). Sb region first written t=1, first
// read t=1 (after barrier) -> no uninitialized reads.
// LDS short-index map: Hb(t) = aggL + (t&1)*2176; Sb(t) = aggL + 4352 +
// (t&1)*2176; all within [0, 8704) < 17408.
// ---------------------------------------------------------------------------
__launch_bounds__(512, 4)
__global__ void fused_recur(const int* __restrict__ base,
                            const int* __restrict__ bsum,
                            const uint2* __restrict__ ep2,
                            const float* __restrict__ nemb,
                            const float* __restrict__ remb,
                            const unsigned short* __restrict__ pack,
                            const float* __restrict__ bz,
                            const float* __restrict__ bh,
                            float* __restrict__ out) {
  __shared__ unsigned short aggL[T_STEPS * 16 * 136];   // 34816 B (agg, then Hb/Sb union)
  int lane = threadIdx.x & 63;
  int nt = threadIdx.x >> 6;        // wave id: owns nodes {2nt,2nt+1} / col tile nt
  int q = lane >> 4, l15 = lane & 15;
  int tile = blockIdx.x;
  int row0 = tile * 16;
  int c = nt * 16 + l15;

  // ---- Phase A: gather this wave's 2 nodes, all 8 t-segments -> aggL ----
#pragma unroll
  for (int ln = 0; ln < 2; ln++) {
    int nl = nt * 2 + ln;                       // local row 0..15
    int kb = (row0 + nl) * T_STEPS;
    int prev = base[kb] + bsum[kb >> 10];
#pragma unroll
    for (int tt = 0; tt < T_STEPS; tt++) {
      int kn = kb + tt + 1;
      int e1 = base[kn] + bsum[kn >> 10];
      float ax = 0.f, ay = 0.f;
      for (int i = prev; i < e1; i++) {
        uint2 e = ep2[i];
        float w = __uint_as_float(e.y);
        int s = e.x & 0x7fff, rt = e.x >> 15;
        float2 sv = ((const float2*)(nemb + (size_t)s * DIM))[lane];
        float2 rv = ((const float2*)(remb + (size_t)rt * DIM))[lane];
        ax += sv.x * rv.x * w;
        ay += sv.y * rv.y * w;
      }
      prev = e1;
      ((unsigned*)&aggL[(tt * 16 + nl) * 136])[lane] = cvt_pk_bf16(ax, ay);
    }
  }
  __syncthreads();

  // ---- Phase B: encoder for ALL steps: H[t](:, nt-cols) as packed bf16 ----
  unsigned hpk[T_STEPS][2];
  {
    short8 wenc[4];
#pragma unroll
    for (int ks = 0; ks < 4; ks++)
      wenc[ks] = *(const short8*)(pack + ((nt * 4 + ks) * 64 + lane) * 8);
#pragma unroll
    for (int t = 0; t < T_STEPS; t++) {
      f32x4 acch = (f32x4){0.f, 0.f, 0.f, 0.f};
#pragma unroll
      for (int ks = 0; ks < 4; ks++) {
        short8 aA = *(const short8*)&aggL[(t * 16 + l15) * 136 + ks * 32 + q * 8];
        acch = __builtin_amdgcn_mfma_f32_16x16x32_bf16(aA, wenc[ks], acch, 0, 0, 0);
      }
      hpk[t][0] = cvt_pk_bf16(fast_tanh(acch[0]), fast_tanh(acch[1]));
      hpk[t][1] = cvt_pk_bf16(fast_tanh(acch[2]), fast_tanh(acch[3]));
    }
  }

  // recurrence weight B-fragments for this wave's nt
  short8 wz[4], uz[4], wh[4], uh[4];
#pragma unroll
  for (int ks = 0; ks < 4; ks++) {
    int fo = ((nt * 4 + ks) * 64 + lane) * 8;
    wz[ks] = *(const short8*)(pack + 16384 * 1 + fo);
    uz[ks] = *(const short8*)(pack + 16384 * 2 + fo);
    wh[ks] = *(const short8*)(pack + 16384 * 3 + fo);
    uh[ks] = *(const short8*)(pack + 16384 * 4 + fo);
  }
  float bzv = bz[c];
  float bhv = bh[c];

  __syncthreads();   // fence: all aggL(agg) reads done before union overwrite

  f32x4 stC = (f32x4){0.f, 0.f, 0.f, 0.f};

  // ---- Phase C: GRU recurrence (union buffers, 4-chain ILP, t=0 S-skip) ----
#pragma unroll
  for (int t = 0; t < T_STEPS; t++) {
    unsigned short* hB = aggL + (t & 1) * 2176;
    unsigned short* sB = aggL + 4352 + (t & 1) * 2176;
    hB[(q * 4 + 0) * 136 + c] = (unsigned short)hpk[t][0];
    hB[(q * 4 + 1) * 136 + c] = (unsigned short)(hpk[t][0] >> 16);
    hB[(q * 4 + 2) * 136 + c] = (unsigned short)hpk[t][1];
    hB[(q * 4 + 3) * 136 + c] = (unsigned short)(hpk[t][1] >> 16);
    if (t > 0) {
      unsigned s01 = cvt_pk_bf16(stC[0], stC[1]);
      unsigned s23 = cvt_pk_bf16(stC[2], stC[3]);
      sB[(q * 4 + 0) * 136 + c] = (unsigned short)s01;
      sB[(q * 4 + 1) * 136 + c] = (unsigned short)(s01 >> 16);
      sB[(q * 4 + 2) * 136 + c] = (unsigned short)s23;
      sB[(q * 4 + 3) * 136 + c] = (unsigned short)(s23 >> 16);
    }
    __syncthreads();

    short8 hA[4], sA[4];
#pragma unroll
    for (int ks = 0; ks < 4; ks++)
      hA[ks] = *(const short8*)&hB[l15 * 136 + ks * 32 + q * 8];
    if (t > 0) {
#pragma unroll
      for (int ks = 0; ks < 4; ks++)
        sA[ks] = *(const short8*)&sB[l15 * 136 + ks * 32 + q * 8];
    }

    f32x4 zh = (f32x4){bzv, bzv, bzv, bzv};
    f32x4 ch = (f32x4){bhv, bhv, bhv, bhv};
    f32x4 zs = (f32x4){0.f, 0.f, 0.f, 0.f};
    f32x4 cs = (f32x4){0.f, 0.f, 0.f, 0.f};
#pragma unroll
    for (int ks = 0; ks < 4; ks++) {
      zh = __builtin_amdgcn_mfma_f32_16x16x32_bf16(hA[ks], wz[ks], zh, 0, 0, 0);
      ch = __builtin_amdgcn_mfma_f32_16x16x32_bf16(hA[ks], wh[ks], ch, 0, 0, 0);
    }
    if (t > 0) {
#pragma unroll
      for (int ks = 0; ks < 4; ks++) {
        zs = __builtin_amdgcn_mfma_f32_16x16x32_bf16(sA[ks], uz[ks], zs, 0, 0, 0);
        cs = __builtin_amdgcn_mfma_f32_16x16x32_bf16(sA[ks], uh[ks], cs, 0, 0, 0);
      }
    }
#pragma unroll
    for (int r = 0; r < 4; r++) {
      float z = fast_sig(zh[r] + zs[r]);
      float cc = fast_tanh(ch[r] + cs[r]);
      stC[r] = (1.f - z) * stC[r] + z * cc;
    }
  }

  // final state -> out (fp32, C-layout positions)
#pragma unroll
  for (int r = 0; r < 4; r++)
    out[(size_t)(row0 + q * 4 + r) * DIM + c] = stC[r];
}

extern "C" void kernel_launch(void* const* d_in, const int* in_sizes, int n_in,
                              void* d_out, int out_size, void* d_ws, size_t ws_size,
                              hipStream_t stream) {
  const int* eidx  = (const int*)d_in[0];
  const int* src   = eidx;
  const int* dst   = eidx + N_EDGES;
  const int* etype = (const int*)d_in[1];
  const int* etime = (const int*)d_in[2];
  const float* ew   = (const float*)d_in[3];
  const float* nemb = (const float*)d_in[4];
  const float* remb = (const float*)d_in[5];
  const float* Wenc = (const float*)d_in[6];
  const float* Wz   = (const float*)d_in[7];
  const float* Uz   = (const float*)d_in[8];
  const float* Wh   = (const float*)d_in[9];
  const float* Uh   = (const float*)d_in[10];
  const float* bz   = (const float*)d_in[11];
  const float* bh   = (const float*)d_in[12];
  // d_in[13] = num_times (constant 8 for this problem's fixed shapes)

  // ws layout
  int* counts = (int*)d_ws;                                        // SCAN_N
  int* cursor = counts + SCAN_N;                                   // KEYS
  int* bsum   = cursor + KEYS;                                     // 256
  int* base   = bsum + 256;                                        // SCAN_N
  uint2* ep2  = (uint2*)(base + ((SCAN_N + 1) & ~1));              // E, 8B-aligned
  unsigned short* pack = (unsigned short*)(ep2 + N_EDGES);         // 5*16384
  float* outp = (float*)d_out;

  hipMemsetAsync(counts, 0, (size_t)(SCAN_N + KEYS) * sizeof(int), stream);
  repack5<<<(5 * 16384 + 255) / 256, 256, 0, stream>>>(Wenc, Wz, Uz, Wh, Uh, pack);
  hist_k<<<(N_EDGES + 255) / 256, 256, 0, stream>>>(dst, etime, counts);
  scan1_k<<<SCAN_BLKS, 256, 0, stream>>>(counts, base, bsum);
  scan2_k<<<1, 256, 0, stream>>>(bsum);
  fill_k<<<(N_EDGES + 255) / 256, 256, 0, stream>>>(src, dst, etype, etime, ew,
                                                    base, bsum, cursor, ep2);
  fused_recur<<<N_TILES, 512, 0, stream>>>(base, bsum, ep2, nemb, remb,
                                           pack, bz, bh, outp);
}

// Round 12
// 194.556 us; speedup vs baseline: 1.3023x; 1.1078x over previous
//
#include <hip/hip_runtime.h>

#define N_NODES 20000
#define N_REL 200
#define N_EDGES 200000
#define DIM 128
#define T_STEPS 8
#define N_TILES (N_NODES / 16)              // 1250
#define KEYS (N_NODES * T_STEPS)            // 160000 (dst,t) segments
#define SCAN_N (KEYS + 1)                   // 160001
#define SCAN_BLKS ((SCAN_N + 1023) / 1024)  // 157

typedef short short8 __attribute__((ext_vector_type(8)));
typedef float f32x4 __attribute__((ext_vector_type(4)));

static __device__ __forceinline__ unsigned short f2bf(float f) {
  union { float f; unsigned u; } v; v.f = f;
  unsigned r = v.u + 0x7fffu + ((v.u >> 16) & 1u);   // RNE
  return (unsigned short)(r >> 16);
}
// packed f32x2 -> bf16x2 (RNE), 1 instruction
static __device__ __forceinline__ unsigned cvt_pk_bf16(float lo, float hi) {
  unsigned r;
  asm("v_cvt_pk_bf16_f32 %0, %1, %2" : "=v"(r) : "v"(lo), "v"(hi));
  return r;
}
static __device__ __forceinline__ float fast_tanh(float x) {
  float e = __expf(2.f * x);           // inf-safe: x>>0 -> 1, x<<0 -> -1
  return 1.f - 2.f / (e + 1.f);
}
static __device__ __forceinline__ float fast_sig(float x) {
  return 1.f / (1.f + __expf(-x));
}

// ---------------------------------------------------------------------------
// Repack the five 128x128 fp32 weight matrices (row-major W[k][n]) into bf16
// MFMA B-fragment order: pack[m][((nt*4+ks)*64+lane)*8+j] = bf16(W[k][n]),
// n = nt*16 + (lane&15), k = ks*32 + (lane>>4)*8 + j.
// Slots: 0=Wenc 1=Wz 2=Uz 3=Wh 4=Uh.
// ---------------------------------------------------------------------------
__global__ void repack5(const float* __restrict__ w0,
                        const float* __restrict__ w1,
                        const float* __restrict__ w2,
                        const float* __restrict__ w3,
                        const float* __restrict__ w4,
                        unsigned short* __restrict__ pack) {
  int i = blockIdx.x * blockDim.x + threadIdx.x;
  if (i >= 5 * 16384) return;
  int m = i >> 14, r = i & 16383;
  int j = r & 7, lane = (r >> 3) & 63, ks = (r >> 9) & 3, nt = (r >> 11) & 7;
  int n = nt * 16 + (lane & 15);
  int k = ks * 32 + (lane >> 4) * 8 + j;
  const float* w = (m == 0) ? w0 : (m == 1) ? w1 : (m == 2) ? w2
                 : (m == 3) ? w3 : w4;
  pack[i] = f2bf(w[k * DIM + n]);
}

// ----------------- CSR build: bucket by key = dst*8 + t --------------------
__global__ void hist_k(const int* __restrict__ dst, const int* __restrict__ etime,
                       int* __restrict__ counts) {
  int i = blockIdx.x * blockDim.x + threadIdx.x;
  if (i >= N_EDGES) return;
  atomicAdd(&counts[dst[i] * T_STEPS + etime[i]], 1);
}

__global__ void scan1_k(const int* __restrict__ counts,
                        int* __restrict__ base, int* __restrict__ bsum) {
  __shared__ int ls[256];
  int tid = threadIdx.x;
  int i0 = blockIdx.x * 1024 + tid * 4;
  int v[4], ts = 0;
#pragma unroll
  for (int r = 0; r < 4; r++) {
    v[r] = (i0 + r < SCAN_N) ? counts[i0 + r] : 0;
    ts += v[r];
  }
  ls[tid] = ts; __syncthreads();
#pragma unroll
  for (int off = 1; off < 256; off <<= 1) {
    int x = (tid >= off) ? ls[tid - off] : 0;
    __syncthreads(); ls[tid] += x; __syncthreads();
  }
  int run = ls[tid] - ts;
  if (tid == 255) bsum[blockIdx.x] = ls[255];
#pragma unroll
  for (int r = 0; r < 4; r++) {
    if (i0 + r < SCAN_N) base[i0 + r] = run;
    run += v[r];
  }
}

__global__ void scan2_k(int* __restrict__ bsum) {
  __shared__ int ls[256];
  int tid = threadIdx.x;
  int v = (tid < SCAN_BLKS) ? bsum[tid] : 0;
  ls[tid] = v; __syncthreads();
#pragma unroll
  for (int off = 1; off < 256; off <<= 1) {
    int x = (tid >= off) ? ls[tid - off] : 0;
    __syncthreads(); ls[tid] += x; __syncthreads();
  }
  if (tid < SCAN_BLKS) bsum[tid] = ls[tid] - v;
}

// ep2 = {src | rel<<15 | t<<23, weight bits}  (t also implicit in segment;
// carried in spare bits so the gather can walk a node's full range).
// scan3 folded in: absolute position = base[key] + bsum[key>>10] + cursor++.
__global__ void fill_k(const int* __restrict__ src, const int* __restrict__ dst,
                       const int* __restrict__ etype, const int* __restrict__ etime,
                       const float* __restrict__ ew,
                       const int* __restrict__ base, const int* __restrict__ bsum,
                       int* __restrict__ cursor, uint2* __restrict__ ep2) {
  int i = blockIdx.x * blockDim.x + threadIdx.x;
  if (i >= N_EDGES) return;
  int t = etime[i];
  int key = dst[i] * T_STEPS + t;
  int pos = base[key] + bsum[key >> 10] + atomicAdd(&cursor[key], 1);
  uint2 e;
  e.x = (unsigned)src[i] | ((unsigned)etype[i] << 15) | ((unsigned)t << 23);
  e.y = __float_as_uint(ew[i]);
  ep2[pos] = e;
}

// ---------------------------------------------------------------------------
// Fully-fused GATHER + encoder + GRU recurrence. One block per 16-node tile,
// 8 waves. Exact R6 structure (best measured: 213.1 us total) except phase A.
// Phase A (gather, NEW): wave wv owns nodes {2wv, 2wv+1}. With t carried in
//   ep2 bits 23-25, each node's WHOLE edge range [base[kb], base[kb+8]) is
//   walked with only 2 boundary loads (was 9) and UNROLLED BY 2: two
//   independent edge load-chains in flight (ep2[i], ep2[i+1] -> both rows'
//   nemb/remb loads issued together) -> ~2x fewer serial latency steps than
//   the segment-by-segment walk (segments avg 1.25 edges, so in-segment
//   unrolling was useless). Accumulation is t-predicated into ax[8]/ay[8]
//   (R0's proven pattern); ONE node at a time -> no boundary arrays, no
//   spills (R9's failure mode; check: WRITE_SIZE must stay 10000 KB).
// ONE barrier, then:
// Phase B (encoder, hoisted): wave nt owns column tile nt; A-frags for all
//   8 t read from aggL (stride 136 shorts: 2-way bank alias = free);
//   32 MFMAs with wenc -> hpk[t] packed bf16 (16 VGPRs).
// Phase C (recurrence, exact R6): per step t: H[t],S -> double-buffered LDS
//   (stride 136), ONE barrier, re-read as A-frags (full 128-K), 16 MFMAs,
//   gated update.
// MFMA 16x16x32_bf16 layouts (HW-verified): A: m=lane&15,k=quad*8+j;
// B: n=lane&15,k=quad*8+j;  C/D: col=lane&15, row=quad*4+reg.
// Double-buffer WAR safety: writes of buffer X at step t+2 are ordered after
// barrier(t+1), which is after all reads of X at step t. aggL is written
// only in phase A (barrier-protected) and read-only afterwards.
// ---------------------------------------------------------------------------
__launch_bounds__(512, 4)
__global__ void fused_recur(const int* __restrict__ base,
                            const int* __restrict__ bsum,
                            const uint2* __restrict__ ep2,
                            const float* __restrict__ nemb,
                            const float* __restrict__ remb,
                            const unsigned short* __restrict__ pack,
                            const float* __restrict__ bz,
                            const float* __restrict__ bh,
                            float* __restrict__ out) {
  __shared__ unsigned short aggL[T_STEPS * 16 * 136];   // 34816 B
  __shared__ unsigned short Hb[2][16 * 136];            //  8704 B
  __shared__ unsigned short Sb[2][16 * 136];            //  8704 B
  int lane = threadIdx.x & 63;
  int nt = threadIdx.x >> 6;        // wave id: owns nodes {2nt,2nt+1} / col tile nt
  int q = lane >> 4, l15 = lane & 15;
  int tile = blockIdx.x;
  int row0 = tile * 16;
  int c = nt * 16 + l15;

  // ---- Phase A: gather this wave's 2 nodes; full-range walk, unroll 2 ----
#pragma unroll
  for (int ln = 0; ln < 2; ln++) {
    int nl = nt * 2 + ln;                       // local row 0..15
    int kb = (row0 + nl) * T_STEPS;
    int ke = kb + T_STEPS;
    int i = base[kb] + bsum[kb >> 10];
    int e1 = base[ke] + bsum[ke >> 10];
    float ax[T_STEPS], ay[T_STEPS];
#pragma unroll
    for (int tt = 0; tt < T_STEPS; tt++) { ax[tt] = 0.f; ay[tt] = 0.f; }
    for (; i + 1 < e1; i += 2) {
      uint2 ea = ep2[i];
      uint2 eb = ep2[i + 1];
      float wa = __uint_as_float(ea.y), wb = __uint_as_float(eb.y);
      int sa = ea.x & 0x7fff, ra = (ea.x >> 15) & 0xff, ta = (ea.x >> 23) & 7;
      int sb = eb.x & 0x7fff, rb = (eb.x >> 15) & 0xff, tb = (eb.x >> 23) & 7;
      float2 sva = ((const float2*)(nemb + (size_t)sa * DIM))[lane];
      float2 svb = ((const float2*)(nemb + (size_t)sb * DIM))[lane];
      float2 rva = ((const float2*)(remb + (size_t)ra * DIM))[lane];
      float2 rvb = ((const float2*)(remb + (size_t)rb * DIM))[lane];
      float m0a = sva.x * rva.x * wa, m1a = sva.y * rva.y * wa;
      float m0b = svb.x * rvb.x * wb, m1b = svb.y * rvb.y * wb;
#pragma unroll
      for (int tt = 0; tt < T_STEPS; tt++) {
        ax[tt] += ((ta == tt) ? m0a : 0.f) + ((tb == tt) ? m0b : 0.f);
        ay[tt] += ((ta == tt) ? m1a : 0.f) + ((tb == tt) ? m1b : 0.f);
      }
    }
    if (i < e1) {
      uint2 ea = ep2[i];
      float wa = __uint_as_float(ea.y);
      int sa = ea.x & 0x7fff, ra = (ea.x >> 15) & 0xff, ta = (ea.x >> 23) & 7;
      float2 sva = ((const float2*)(nemb + (size_t)sa * DIM))[lane];
      float2 rva = ((const float2*)(remb + (size_t)ra * DIM))[lane];
      float m0a = sva.x * rva.x * wa, m1a = sva.y * rva.y * wa;
#pragma unroll
      for (int tt = 0; tt < T_STEPS; tt++) {
        ax[tt] += (ta == tt) ? m0a : 0.f;
        ay[tt] += (ta == tt) ? m1a : 0.f;
      }
    }
#pragma unroll
    for (int tt = 0; tt < T_STEPS; tt++)
      ((unsigned*)&aggL[(tt * 16 + nl) * 136])[lane] = cvt_pk_bf16(ax[tt], ay[tt]);
  }
  __syncthreads();

  // ---- Phase B: encoder for ALL steps: H[t](:, nt-cols) as packed bf16 ----
  unsigned hpk[T_STEPS][2];
  {
    short8 wenc[4];
#pragma unroll
    for (int ks = 0; ks < 4; ks++)
      wenc[ks] = *(const short8*)(pack + ((nt * 4 + ks) * 64 + lane) * 8);
#pragma unroll
    for (int t = 0; t < T_STEPS; t++) {
      f32x4 acch = (f32x4){0.f, 0.f, 0.f, 0.f};
#pragma unroll
      for (int ks = 0; ks < 4; ks++) {
        short8 aA = *(const short8*)&aggL[(t * 16 + l15) * 136 + ks * 32 + q * 8];
        acch = __builtin_amdgcn_mfma_f32_16x16x32_bf16(aA, wenc[ks], acch, 0, 0, 0);
      }
      hpk[t][0] = cvt_pk_bf16(fast_tanh(acch[0]), fast_tanh(acch[1]));
      hpk[t][1] = cvt_pk_bf16(fast_tanh(acch[2]), fast_tanh(acch[3]));
    }
  }

  // recurrence weight B-fragments for this wave's nt
  short8 wz[4], uz[4], wh[4], uh[4];
#pragma unroll
  for (int ks = 0; ks < 4; ks++) {
    int fo = ((nt * 4 + ks) * 64 + lane) * 8;
    wz[ks] = *(const short8*)(pack + 16384 * 1 + fo);
    uz[ks] = *(const short8*)(pack + 16384 * 2 + fo);
    wh[ks] = *(const short8*)(pack + 16384 * 3 + fo);
    uh[ks] = *(const short8*)(pack + 16384 * 4 + fo);
  }
  float bzv = bz[c];
  float bhv = bh[c];

  f32x4 stC = (f32x4){0.f, 0.f, 0.f, 0.f};

  // ---- Phase C: GRU recurrence (exact R6 best-measured form) ----
#pragma unroll
  for (int t = 0; t < T_STEPS; t++) {
    unsigned short* hB = Hb[t & 1];
    unsigned short* sB = Sb[t & 1];
    unsigned s01 = cvt_pk_bf16(stC[0], stC[1]);
    unsigned s23 = cvt_pk_bf16(stC[2], stC[3]);
    hB[(q * 4 + 0) * 136 + c] = (unsigned short)hpk[t][0];
    hB[(q * 4 + 1) * 136 + c] = (unsigned short)(hpk[t][0] >> 16);
    hB[(q * 4 + 2) * 136 + c] = (unsigned short)hpk[t][1];
    hB[(q * 4 + 3) * 136 + c] = (unsigned short)(hpk[t][1] >> 16);
    sB[(q * 4 + 0) * 136 + c] = (unsigned short)s01;
    sB[(q * 4 + 1) * 136 + c] = (unsigned short)(s01 >> 16);
    sB[(q * 4 + 2) * 136 + c] = (unsigned short)s23;
    sB[(q * 4 + 3) * 136 + c] = (unsigned short)(s23 >> 16);
    __syncthreads();

    f32x4 accz = (f32x4){bzv, bzv, bzv, bzv};
    f32x4 accc = (f32x4){bhv, bhv, bhv, bhv};
#pragma unroll
    for (int ks = 0; ks < 4; ks++) {
      short8 hA = *(const short8*)&hB[l15 * 136 + ks * 32 + q * 8];
      short8 sA = *(const short8*)&sB[l15 * 136 + ks * 32 + q * 8];
      accz = __builtin_amdgcn_mfma_f32_16x16x32_bf16(hA, wz[ks], accz, 0, 0, 0);
      accz = __builtin_amdgcn_mfma_f32_16x16x32_bf16(sA, uz[ks], accz, 0, 0, 0);
      accc = __builtin_amdgcn_mfma_f32_16x16x32_bf16(hA, wh[ks], accc, 0, 0, 0);
      accc = __builtin_amdgcn_mfma_f32_16x16x32_bf16(sA, uh[ks], accc, 0, 0, 0);
    }
#pragma unroll
    for (int r = 0; r < 4; r++) {
      float z = fast_sig(accz[r]);
      float cc = fast_tanh(accc[r]);
      stC[r] = (1.f - z) * stC[r] + z * cc;
    }
  }

  // final state -> out (fp32, C-layout positions)
#pragma unroll
  for (int r = 0; r < 4; r++)
    out[(size_t)(row0 + q * 4 + r) * DIM + c] = stC[r];
}

extern "C" void kernel_launch(void* const* d_in, const int* in_sizes, int n_in,
                              void* d_out, int out_size, void* d_ws, size_t ws_size,
                              hipStream_t stream) {
  const int* eidx  = (const int*)d_in[0];
  const int* src   = eidx;
  const int* dst   = eidx + N_EDGES;
  const int* etype = (const int*)d_in[1];
  const int* etime = (const int*)d_in[2];
  const float* ew   = (const float*)d_in[3];
  const float* nemb = (const float*)d_in[4];
  const float* remb = (const float*)d_in[5];
  const float* Wenc = (const float*)d_in[6];
  const float* Wz   = (const float*)d_in[7];
  const float* Uz   = (const float*)d_in[8];
  const float* Wh   = (const float*)d_in[9];
  const float* Uh   = (const float*)d_in[10];
  const float* bz   = (const float*)d_in[11];
  const float* bh   = (const float*)d_in[12];
  // d_in[13] = num_times (constant 8 for this problem's fixed shapes)

  // ws layout
  int* counts = (int*)d_ws;                                        // SCAN_N
  int* cursor = counts + SCAN_N;                                   // KEYS
  int* bsum   = cursor + KEYS;                                     // 256
  int* base   = bsum + 256;                                        // SCAN_N
  uint2* ep2  = (uint2*)(base + ((SCAN_N + 1) & ~1));              // E, 8B-aligned
  unsigned short* pack = (unsigned short*)(ep2 + N_EDGES);         // 5*16384
  float* outp = (float*)d_out;

  hipMemsetAsync(counts, 0, (size_t)(SCAN_N + KEYS) * sizeof(int), stream);
  repack5<<<(5 * 16384 + 255) / 256, 256, 0, stream>>>(Wenc, Wz, Uz, Wh, Uh, pack);
  hist_k<<<(N_EDGES + 255) / 256, 256, 0, stream>>>(dst, etime, counts);
  scan1_k<<<SCAN_BLKS, 256, 0, stream>>>(counts, base, bsum);
  scan2_k<<<1, 256, 0, stream>>>(bsum);
  fill_k<<<(N_EDGES + 255) / 256, 256, 0, stream>>>(src, dst, etype, etime, ew,
                                                    base, bsum, cursor, ep2);
  fused_recur<<<N_TILES, 512, 0, stream>>>(base, bsum, ep2, nemb, remb,
                                           pack, bz, bh, outp);
}